// Round 1
// baseline (392.359 us; speedup 1.0000x reference)
//
#include <hip/hip_runtime.h>
#include <stdint.h>

// ---------------------------------------------------------------------------
// Spiking network (LIF -> RUM -> LIF with PostPre STDP + MSTDP), 500 steps.
// Persistent producer/consumer pipeline, weights register-resident.
//   producers (256 blocks): 4 hidden cols each (1 col per wave), publish the
//     4 hidden spikes of step t as ONE u32 word (data == ready-flag).
//   consumers (512 blocks): 4 output cols each (1 col per wave), spin-free in
//     steady state via depth-2 prefetch of the 256 spike words.
// No grid barriers, no fences: each packet is a single atomic u32.
// ---------------------------------------------------------------------------

#define DECAY_V  0.90483741803595952f   // exp(-1/10), f64 rounded to f32 like np
#define DECAY_TR 0.95122942450071403f   // exp(-1/20)
#define DECAY_PM 0.95122942450071403f   // exp(-1/20)
#define REST_F   (-70.0f)
#define RESET_F  (-65.0f)
#define THRESH_F (-55.0f)
#define ALPHA_F  (0.95f)
#define BETA_F   (0.8f)
#define NU1_PRE_F  (0.001f)
#define NU1_POST_F (0.01f)
#define NU2_F      (0.0001f)
#define GAIN_F     (20.0f)

static constexpr int IN_D  = 544;
static constexpr int HID_D = 1024;
static constexpr int OUT_D = 2048;
static constexpr int NPROD = HID_D / 4;    // 256 producer blocks
static constexpr int NCONS = OUT_D / 4;    // 512 consumer blocks
static constexpr int NBLK  = NPROD + NCONS; // 768
static constexpr uint32_t SENT = 0xFFFFFFFFu; // valid words are <= 0x01010101

__global__ void init_mask_kernel(uint32_t* __restrict__ mask,
                                 const int* __restrict__ Tp) {
    const int n = Tp[0] * NPROD;
    for (int i = blockIdx.x * blockDim.x + threadIdx.x; i < n;
         i += gridDim.x * blockDim.x)
        mask[i] = SENT;
}

__global__ __launch_bounds__(256, 4)
void snn_kernel(const float* __restrict__ x,
                const float* __restrict__ w1,
                const float* __restrict__ w2,
                const int* __restrict__ Tp,
                float* __restrict__ out,
                uint32_t* __restrict__ mask)
{
    const int T    = Tp[0];
    const int b    = blockIdx.x;
    const int tid  = threadIdx.x;
    const int lane = tid & 63;
    const int wv   = tid >> 6;   // wave 0..3

    __shared__ float sh4[2][4];
    __shared__ __align__(16) float shf[HID_D];

    if (b % 3 == 0) {
        // ----------------- producer: hidden columns p*4 .. p*4+3 -----------------
        const int p   = b / 3;          // 0..255
        const int col = p * 4 + wv;     // this wave's hidden column

        // lane owns input rows lane, lane+64, ..., lane+512 (9 for lane<32, else 8;
        // the invalid 9th row is padded with w=0, rate=0 so it never spikes).
        float w[9], v_in[9], tr_in[9], rate[9];
        #pragma unroll
        for (int k = 0; k < 9; ++k) {
            const int  i  = lane + 64 * k;
            const bool ok = (i < IN_D);
            w[k]     = ok ? w1[i * HID_D + col] : 0.0f;
            rate[k]  = ok ? x[i] * GAIN_F : 0.0f;
            v_in[k]  = REST_F;
            tr_in[k] = 0.0f;
        }
        float v_h = 0.0f, b_h = 0.0f, tr_h = 0.0f;  // replicated across lanes

        for (int t = 0; t < T; ++t) {
            // input LIF (replicated per wave) + i_hid partial for this column
            float acc = 0.0f;
            float s_in[9];
            #pragma unroll
            for (int k = 0; k < 9; ++k) {
                const float v = DECAY_V * (v_in[k] - REST_F) + REST_F + rate[k];
                const bool  sp = (v >= THRESH_F);
                const float s  = sp ? 1.0f : 0.0f;
                v_in[k]  = sp ? RESET_F : v;
                tr_in[k] = sp ? 1.0f : tr_in[k] * DECAY_TR;
                s_in[k]  = s;
                acc = fmaf(s, w[k], acc);
            }
            #pragma unroll
            for (int off = 32; off > 0; off >>= 1)
                acc += __shfl_xor(acc, off, 64);
            // hidden RUM neuron (identical on all lanes)
            const float vh = ALPHA_F * v_h + acc;
            const bool  hp = (vh >= 1.0f + b_h);
            const float sh = hp ? 1.0f : 0.0f;
            v_h  = hp ? 0.0f : vh;
            b_h  = BETA_F * b_h + sh;
            tr_h = hp ? 1.0f : tr_h * DECAY_TR;
            // PostPre STDP on this w1 column (clip keeps w in [0,1])
            const float apot = NU1_POST_F * sh;
            const float adep = NU1_PRE_F * tr_h;
            #pragma unroll
            for (int k = 0; k < 9; ++k) {
                const float nw = w[k] + apot * tr_in[k] - adep * s_in[k];
                w[k] = fminf(fmaxf(nw, 0.0f), 1.0f);
            }
            // publish the block's 4 spikes as one u32 (data doubles as flag)
            const int par = t & 1;
            if (lane == 0) sh4[par][wv] = sh;
            __syncthreads();
            if (tid == 0) {
                const uint32_t word = (uint32_t)sh4[par][0]
                                    | ((uint32_t)sh4[par][1] << 8)
                                    | ((uint32_t)sh4[par][2] << 16)
                                    | ((uint32_t)sh4[par][3] << 24);
                __hip_atomic_store(&mask[t * NPROD + p], word,
                                   __ATOMIC_RELAXED, __HIP_MEMORY_SCOPE_AGENT);
            }
        }
    } else {
        // ----------------- consumer: output columns cb*4 .. cb*4+3 ----------------
        const int cb  = b - b / 3 - 1;  // 0..511
        const int col = cb * 4 + wv;    // this wave's output column

        // lane owns w2 rows lane+64k, k=0..15, for its column (16 VGPRs)
        float w2r[16], pp[16];
        #pragma unroll
        for (int k = 0; k < 16; ++k) {
            w2r[k] = w2[(lane + 64 * k) * OUT_D + col];
            pp[k]  = 0.0f;
        }
        float v_o = REST_F, pm = 0.0f;  // replicated across lanes of the wave

        // depth-2 prefetch pipeline over the 256 spike words per step
        uint32_t cur = __hip_atomic_load(&mask[tid], __ATOMIC_RELAXED,
                                         __HIP_MEMORY_SCOPE_AGENT);
        uint32_t nxt = (T > 1) ? __hip_atomic_load(&mask[NPROD + tid],
                                                   __ATOMIC_RELAXED,
                                                   __HIP_MEMORY_SCOPE_AGENT)
                               : 0u;

        for (int t = 0; t < T; ++t) {
            while (cur == SENT) {
                __builtin_amdgcn_s_sleep(1);
                cur = __hip_atomic_load(&mask[t * NPROD + tid],
                                        __ATOMIC_RELAXED, __HIP_MEMORY_SCOPE_AGENT);
            }
            // expand word tid (hidden cols 4*tid..4*tid+3) into LDS floats
            ((float4*)shf)[tid] = make_float4((float)(cur & 1u),
                                              (float)((cur >> 8) & 1u),
                                              (float)((cur >> 16) & 1u),
                                              (float)((cur >> 24) & 1u));
            __syncthreads();
            // issue prefetch for t+2 early; latency hides under compute
            uint32_t pre = 0u;
            if (t + 2 < T)
                pre = __hip_atomic_load(&mask[(t + 2) * NPROD + tid],
                                        __ATOMIC_RELAXED, __HIP_MEMORY_SCOPE_AGENT);

            float acc = 0.0f, shv[16];
            #pragma unroll
            for (int k = 0; k < 16; ++k) {
                const float s = shf[lane + 64 * k];
                shv[k] = s;
                acc    = fmaf(s, w2r[k], acc);          // i_out partial (old w2)
                pp[k]  = fmaf(pp[k], DECAY_PM, s);      // p_plus = d*p_plus + s_hid
            }
            #pragma unroll
            for (int off = 32; off > 0; off >>= 1)
                acc += __shfl_xor(acc, off, 64);
            // output LIF (identical on all lanes)
            const float v  = DECAY_V * (v_o - REST_F) + REST_F + acc;
            const bool  op = (v >= THRESH_F);
            const float so = op ? 1.0f : 0.0f;
            v_o = op ? RESET_F : v;
            pm  = DECAY_PM * pm - so;                   // p_minus = d*p_minus - s_out
            // MSTDP: w2 += NU2*(p_plus*s_out + s_hid*p_minus)
            const float c1 = NU2_F * so;
            const float c2 = NU2_F * pm;
            #pragma unroll
            for (int k = 0; k < 16; ++k)
                w2r[k] = fmaf(c1, pp[k], fmaf(c2, shv[k], w2r[k]));

            if (lane == 0) out[t * OUT_D + col] = so;
            __syncthreads();   // all shf reads done before next step's writes
            cur = nxt;
            nxt = pre;
        }
    }
}

extern "C" void kernel_launch(void* const* d_in, const int* in_sizes, int n_in,
                              void* d_out, int out_size, void* d_ws, size_t ws_size,
                              hipStream_t stream) {
    const float* x  = (const float*)d_in[0];
    const float* w1 = (const float*)d_in[1];
    const float* w2 = (const float*)d_in[2];
    const int*   Tp = (const int*)d_in[3];
    float*       out  = (float*)d_out;
    uint32_t*    mask = (uint32_t*)d_ws;   // T*256 u32 words (~500 KB for T=500)

    // reset spike-word sentinels every call (replay-safe)
    hipLaunchKernelGGL(init_mask_kernel, dim3(256), dim3(256), 0, stream, mask, Tp);
    hipLaunchKernelGGL(snn_kernel, dim3(NBLK), dim3(256), 0, stream,
                       x, w1, w2, Tp, out, mask);
}